// Round 6
// baseline (243.225 us; speedup 1.0000x reference)
//
#include <hip/hip_runtime.h>

// YOLO loss forward on MI355X.
// input/target: (B=256, C=25, S=64, S=64) fp32, row-major.
// Memory-bound reduction: 209.7 MB -> 1 float. Copy roofline ~33 us.
//
// V7: strictly copy-shaped class pass. Six rounds of evidence: delivered
// rate is set by the address stream of the value loads. Any per-item
// plane-gather addressing caps at 2.5-3.9 TB/s; a pure linear float4
// sweep (m13) hits 6.3 TB/s. So:
//  - flat_class_kernel sweeps BOTH tensors fully linearly (a = t + i*stride,
//    identical address stream to a device copy), consuming with
//    weight = (ch >= 5) * mask. Channels 0..4 are read and zero-weighted
//    (42 MB deliberate waste, ~7 us, to keep the address stream linear).
//    ch is wave-uniform (1024 float4/plane, 16 waves/plane).
//  - mask: 1 MB uchar4 workspace, L2-hot, coalesced 4 B/lane reads.
//  - box_kernel: channels 0..4 gather (42 MB), unchanged known shape.

#define COORD 5.0f
#define NOOBJ 0.5f

constexpr int B = 256;
constexpr int C = 25;
constexpr int S = 64;
constexpr int SS = S * S;                    // 4096 spatial positions per image
constexpr int CH_STRIDE4 = SS / 4;           // 1024 float4 per channel plane
constexpr int IMG_STRIDE4 = C * CH_STRIDE4;  // 25600 float4 per image
constexpr int N4 = B * SS / 4;               // 262144 float4-groups (= 2^18)
constexpr int N_FLAT = B * IMG_STRIDE4;      // 6,553,600 float4 per tensor

constexpr int THREADS = 256;
constexpr int FLAT_BLOCKS = 2560;
constexpr int FLAT_THREADS_TOT = FLAT_BLOCKS * THREADS;  // 655,360
constexpr int FLAT_IPT = N_FLAT / FLAT_THREADS_TOT;      // 10 items/thread
constexpr int BOX_BLOCKS = N4 / THREADS;                 // 1024
constexpr int MASK_BYTES = N4 * 4;                       // uchar4 per group, 1 MB

__device__ __forceinline__ float comp(const float4 v, int k) {
    switch (k) {
        case 0: return v.x;
        case 1: return v.y;
        case 2: return v.z;
        default: return v.w;
    }
}

__device__ __forceinline__ void block_reduce_atomic(float acc, float* out) {
    #pragma unroll
    for (int off = 32; off > 0; off >>= 1)
        acc += __shfl_down(acc, off, 64);
    __shared__ float smem[4];
    const int lane = threadIdx.x & 63;
    const int wid = threadIdx.x >> 6;
    if (lane == 0) smem[wid] = acc;
    __syncthreads();
    if (threadIdx.x == 0) {
        atomicAdd(out, smem[0] + smem[1] + smem[2] + smem[3]);
    }
}

__global__ void zero_out_kernel(float* out) { out[0] = 0.0f; }

// uchar4 objectness mask per float4-group: mask[g] = (t4 > 0)
__global__ __launch_bounds__(256) void mask_kernel(
        const float4* __restrict__ tg, uchar4* __restrict__ mask) {
    const int g = blockIdx.x * 256 + threadIdx.x;  // grid = N4/256 = 1024 blocks
    const float4 t4 = tg[(g >> 10) * IMG_STRIDE4 + (g & 1023) + 4 * CH_STRIDE4];
    mask[g] = make_uchar4(t4.x > 0.0f, t4.y > 0.0f, t4.z > 0.0f, t4.w > 0.0f);
}

// ---- class terms, copy-shaped ----
// Linear sweep over all 25 channels; weight = (ch >= 5) * mask[g].
__global__ __launch_bounds__(256) void flat_class_kernel(
        const float4* __restrict__ in, const float4* __restrict__ tg,
        const uchar4* __restrict__ mask,  // may be null -> derive from tg
        float* __restrict__ out) {
    const int t = blockIdx.x * THREADS + threadIdx.x;
    float acc = 0.0f;

    #pragma unroll
    for (int i = 0; i < FLAT_IPT; i += 2) {
        const int a0 = t + (i + 0) * FLAT_THREADS_TOT;   // linear float4 index
        const int a1 = t + (i + 1) * FLAT_THREADS_TOT;

        // value loads: address stream identical to a device copy
        const float4 pv0 = in[a0];
        const float4 tv0 = tg[a0];
        const float4 pv1 = in[a1];
        const float4 tv1 = tg[a1];

        // index math (off the load critical path; ch is wave-uniform)
        const int img0 = a0 / IMG_STRIDE4;               // magic-mul
        const int img1 = a1 / IMG_STRIDE4;
        const int r0 = a0 - img0 * IMG_STRIDE4;
        const int r1 = a1 - img1 * IMG_STRIDE4;
        const int ch0 = r0 >> 10;
        const int ch1 = r1 >> 10;
        const float cw0 = (ch0 >= 5) ? 1.0f : 0.0f;
        const float cw1 = (ch1 >= 5) ? 1.0f : 0.0f;
        const int g0 = (img0 << 10) + (r0 & 1023);
        const int g1 = (img1 << 10) + (r1 & 1023);

        float w0x, w0y, w0z, w0w, w1x, w1y, w1z, w1w;
        if (mask) {
            const uchar4 mk0 = mask[g0];
            const uchar4 mk1 = mask[g1];
            w0x = cw0 * mk0.x; w0y = cw0 * mk0.y;
            w0z = cw0 * mk0.z; w0w = cw0 * mk0.w;
            w1x = cw1 * mk1.x; w1y = cw1 * mk1.y;
            w1z = cw1 * mk1.z; w1w = cw1 * mk1.w;
        } else {
            const float4 ta = tg[(g0 >> 10) * IMG_STRIDE4 + (g0 & 1023) + 4 * CH_STRIDE4];
            const float4 tb = tg[(g1 >> 10) * IMG_STRIDE4 + (g1 & 1023) + 4 * CH_STRIDE4];
            w0x = cw0 * (ta.x > 0.0f ? 1.0f : 0.0f);
            w0y = cw0 * (ta.y > 0.0f ? 1.0f : 0.0f);
            w0z = cw0 * (ta.z > 0.0f ? 1.0f : 0.0f);
            w0w = cw0 * (ta.w > 0.0f ? 1.0f : 0.0f);
            w1x = cw1 * (tb.x > 0.0f ? 1.0f : 0.0f);
            w1y = cw1 * (tb.y > 0.0f ? 1.0f : 0.0f);
            w1z = cw1 * (tb.z > 0.0f ? 1.0f : 0.0f);
            w1w = cw1 * (tb.w > 0.0f ? 1.0f : 0.0f);
        }

        float d;
        d = pv0.x - tv0.x; acc = fmaf(w0x * d, d, acc);
        d = pv0.y - tv0.y; acc = fmaf(w0y * d, d, acc);
        d = pv0.z - tv0.z; acc = fmaf(w0z * d, d, acc);
        d = pv0.w - tv0.w; acc = fmaf(w0w * d, d, acc);
        d = pv1.x - tv1.x; acc = fmaf(w1x * d, d, acc);
        d = pv1.y - tv1.y; acc = fmaf(w1y * d, d, acc);
        d = pv1.z - tv1.z; acc = fmaf(w1z * d, d, acc);
        d = pv1.w - tv1.w; acc = fmaf(w1w * d, d, acc);
    }

    block_reduce_atomic(acc, out);
}

// ---- box terms: channels 0..4 (coord + iou + conf + noobj) ----
__global__ __launch_bounds__(256) void box_kernel(
        const float4* __restrict__ in, const float4* __restrict__ tg,
        float* __restrict__ out) {
    const int g = blockIdx.x * THREADS + threadIdx.x;  // < N4
    const int base = (g >> 10) * IMG_STRIDE4 + (g & 1023);

    const float4 p0 = in[base + 0 * CH_STRIDE4];
    const float4 p1 = in[base + 1 * CH_STRIDE4];
    const float4 p2 = in[base + 2 * CH_STRIDE4];
    const float4 p3 = in[base + 3 * CH_STRIDE4];
    const float4 p4 = in[base + 4 * CH_STRIDE4];
    const float4 t0 = tg[base + 0 * CH_STRIDE4];
    const float4 t1 = tg[base + 1 * CH_STRIDE4];
    const float4 t2 = tg[base + 2 * CH_STRIDE4];
    const float4 t3 = tg[base + 3 * CH_STRIDE4];
    const float4 t4 = tg[base + 4 * CH_STRIDE4];

    float acc = 0.0f;
    const float invBlocks = 1.0f / (float)S;
    #pragma unroll
    for (int k = 0; k < 4; ++k) {
        const float px = comp(p0, k), py = comp(p1, k);
        const float pw = comp(p2, k), ph = comp(p3, k);
        const float pc = comp(p4, k);
        const float tx = comp(t0, k), ty = comp(t1, k);
        const float tw = comp(t2, k), th = comp(t3, k);
        const float tc = comp(t4, k);
        const float m = (tc > 0.0f) ? 1.0f : 0.0f;

        // IoU (forward values only)
        const float c1x = px * invBlocks, c1y = py * invBlocks;
        const float c2x = tx * invBlocks, c2y = ty * invBlocks;
        const float x1a = c1x - pw * 0.5f, x2a = c1x + pw * 0.5f;
        const float y1a = c1y - ph * 0.5f, y2a = c1y + ph * 0.5f;
        const float x1b = c2x - tw * 0.5f, x2b = c2x + tw * 0.5f;
        const float y1b = c2y - th * 0.5f, y2b = c2y + th * 0.5f;
        const float dx = fminf(x2a, x2b) - fmaxf(x1a, x1b);
        const float dy = fminf(y2a, y2b) - fmaxf(y1a, y1b);
        const float inter = dx * dy;
        const float uni = pw * ph + tw * th - inter;
        const bool pos = (dx > 0.0f) && (dy > 0.0f);
        const float iou = pos ? (inter / uni) : 0.0f;

        // coord terms
        const float ex = px - tx, ey = py - ty;
        acc += COORD * m * (ex * ex + ey * ey);
        const float sw = sqrtf(pw) - sqrtf(tw);
        const float sh = sqrtf(ph) - sqrtf(th);
        acc += COORD * m * (sw * sw + sh * sh);
        // confidence terms
        const float ec = pc - iou;
        acc += m * ec * ec;
        acc += NOOBJ * (1.0f - m) * (pc * pc);
    }

    block_reduce_atomic(acc, out);
}

extern "C" void kernel_launch(void* const* d_in, const int* in_sizes, int n_in,
                              void* d_out, int out_size, void* d_ws, size_t ws_size,
                              hipStream_t stream) {
    const float4* in = (const float4*)d_in[0];
    const float4* tg = (const float4*)d_in[1];
    float* out = (float*)d_out;

    // d_out is re-poisoned to 0xAA before every timed launch -> zero it first.
    zero_out_kernel<<<1, 1, 0, stream>>>(out);

    uchar4* mask = nullptr;
    if (d_ws != nullptr && ws_size >= (size_t)MASK_BYTES) {
        mask = (uchar4*)d_ws;
        mask_kernel<<<N4 / 256, 256, 0, stream>>>(tg, mask);
    }

    flat_class_kernel<<<FLAT_BLOCKS, THREADS, 0, stream>>>(in, tg, mask, out);
    box_kernel<<<BOX_BLOCKS, THREADS, 0, stream>>>(in, tg, out);
}

// Round 7
// 228.029 us; speedup vs baseline: 1.0666x; 1.0666x over previous
//
#include <hip/hip_runtime.h>

// YOLO loss forward on MI355X.
// input/target: (B=256, C=25, S=64, S=64) fp32, row-major.
// Memory-bound reduction: 209.7 MB -> 1 float.
//
// V8: per-wave MLP via explicit multi-buffer rotation. Seven rounds of
// evidence: delivered rate tracks bytes-in-flight per wave (Little's law,
// ~4 KB/CU in flight in all prior variants); addressing pattern, occupancy,
// and VGPR budget are all falsified as levers. The compiler sinks loads to
// minimize pressure (V5), so the rotation is pinned with
// __builtin_amdgcn_sched_barrier(0) after each load batch: loads may hoist
// but can never sink below their consumes.
//  - class: thread = one float4-group x 10 channels; ONE t4 load gives the
//    mask for all 10 items (mask stream eliminated; no workspace/kernel).
//    5 channel-pairs through a 3-buffer pipeline: 12 value loads always
//    in flight. Traffic 176 MB (the minimum).
//  - box: 2 groups/thread, both 10-load bursts issued before any consume
//    (20 KB/wave in flight), launch_bounds(256,2) for register room.

#define COORD 5.0f
#define NOOBJ 0.5f

constexpr int B = 256;
constexpr int C = 25;
constexpr int S = 64;
constexpr int SS = S * S;                    // 4096 spatial positions per image
constexpr int CH_STRIDE4 = SS / 4;           // 1024 float4 per channel plane
constexpr int IMG_STRIDE4 = C * CH_STRIDE4;  // 25600 float4 per image
constexpr int N4 = B * SS / 4;               // 262144 float4-groups (= 2^18)

constexpr int THREADS = 256;
constexpr int CLASS_T_TOT = 2 * N4;                  // halves: ch 5-14 / 15-24
constexpr int CLASS_BLOCKS = CLASS_T_TOT / THREADS;  // 2048
constexpr int BOX_BLOCKS = (N4 / 2) / THREADS;       // 512 (2 groups/thread)

__device__ __forceinline__ float comp(const float4 v, int k) {
    switch (k) {
        case 0: return v.x;
        case 1: return v.y;
        case 2: return v.z;
        default: return v.w;
    }
}

__device__ __forceinline__ void block_reduce_atomic(float acc, float* out) {
    #pragma unroll
    for (int off = 32; off > 0; off >>= 1)
        acc += __shfl_down(acc, off, 64);
    __shared__ float smem[4];
    const int lane = threadIdx.x & 63;
    const int wid = threadIdx.x >> 6;
    if (lane == 0) smem[wid] = acc;
    __syncthreads();
    if (threadIdx.x == 0) {
        atomicAdd(out, smem[0] + smem[1] + smem[2] + smem[3]);
    }
}

__global__ void zero_out_kernel(float* out) { out[0] = 0.0f; }

// weighted sum of squared diffs for one channel-pair (8 components)
__device__ __forceinline__ void sq8(const float4 p0, const float4 t0,
                                    const float4 p1, const float4 t1,
                                    float mx, float my, float mz, float mw,
                                    float& acc) {
    float d;
    d = p0.x - t0.x; acc = fmaf(mx * d, d, acc);
    d = p0.y - t0.y; acc = fmaf(my * d, d, acc);
    d = p0.z - t0.z; acc = fmaf(mz * d, d, acc);
    d = p0.w - t0.w; acc = fmaf(mw * d, d, acc);
    d = p1.x - t1.x; acc = fmaf(mx * d, d, acc);
    d = p1.y - t1.y; acc = fmaf(my * d, d, acc);
    d = p1.z - t1.z; acc = fmaf(mz * d, d, acc);
    d = p1.w - t1.w; acc = fmaf(mw * d, d, acc);
}

// ---- class terms: sum m * (p_c - t_c)^2 over channels 5..24 ----
// Thread T: group g = T & (N4-1), channels c0..c0+9 where c0 = 5 + (T>>18)*10.
__global__ __launch_bounds__(256, 4) void class_kernel(
        const float4* __restrict__ in, const float4* __restrict__ tg,
        float* __restrict__ out) {
    const int T = blockIdx.x * THREADS + threadIdx.x;   // < 2*N4
    const int g = T & (N4 - 1);
    const int half = T >> 18;                            // 0 or 1
    const int base = (g >> 10) * IMG_STRIDE4 + (g & 1023);
    const int c0 = 5 + half * 10;
    const float4* inp = in + base + c0 * CH_STRIDE4;
    const float4* tgp = tg + base + c0 * CH_STRIDE4;

    // one mask load, reused by all 10 channels
    const float4 t4 = tg[base + 4 * CH_STRIDE4];

    // prologue: 3 channel-pairs (12 value loads) in flight
    float4 pA0 = inp[0 * 1024], tA0 = tgp[0 * 1024];
    float4 pA1 = inp[1 * 1024], tA1 = tgp[1 * 1024];
    float4 pB0 = inp[2 * 1024], tB0 = tgp[2 * 1024];
    float4 pB1 = inp[3 * 1024], tB1 = tgp[3 * 1024];
    float4 pC0 = inp[4 * 1024], tC0 = tgp[4 * 1024];
    float4 pC1 = inp[5 * 1024], tC1 = tgp[5 * 1024];
    __builtin_amdgcn_sched_barrier(0);   // loads may not sink below here

    const float mx = t4.x > 0.0f ? 1.0f : 0.0f;
    const float my = t4.y > 0.0f ? 1.0f : 0.0f;
    const float mz = t4.z > 0.0f ? 1.0f : 0.0f;
    const float mw = t4.w > 0.0f ? 1.0f : 0.0f;

    float acc = 0.0f;

    // steady state: always >= 2 pairs (8 loads) outstanding behind a consume
    sq8(pA0, tA0, pA1, tA1, mx, my, mz, mw, acc);        // P0
    pA0 = inp[6 * 1024]; tA0 = tgp[6 * 1024];            // issue P3
    pA1 = inp[7 * 1024]; tA1 = tgp[7 * 1024];
    __builtin_amdgcn_sched_barrier(0);

    sq8(pB0, tB0, pB1, tB1, mx, my, mz, mw, acc);        // P1
    pB0 = inp[8 * 1024]; tB0 = tgp[8 * 1024];            // issue P4
    pB1 = inp[9 * 1024]; tB1 = tgp[9 * 1024];
    __builtin_amdgcn_sched_barrier(0);

    sq8(pC0, tC0, pC1, tC1, mx, my, mz, mw, acc);        // P2
    sq8(pA0, tA0, pA1, tA1, mx, my, mz, mw, acc);        // P3
    sq8(pB0, tB0, pB1, tB1, mx, my, mz, mw, acc);        // P4

    block_reduce_atomic(acc, out);
}

// box-term math for one float4-group (channels 0..4 of both tensors)
__device__ __forceinline__ void boxAccum(
        const float4 p0, const float4 p1, const float4 p2, const float4 p3,
        const float4 p4, const float4 t0, const float4 t1, const float4 t2,
        const float4 t3, const float4 t4, float& acc) {
    const float invBlocks = 1.0f / (float)S;
    #pragma unroll
    for (int k = 0; k < 4; ++k) {
        const float px = comp(p0, k), py = comp(p1, k);
        const float pw = comp(p2, k), ph = comp(p3, k);
        const float pc = comp(p4, k);
        const float tx = comp(t0, k), ty = comp(t1, k);
        const float tw = comp(t2, k), th = comp(t3, k);
        const float tc = comp(t4, k);
        const float m = (tc > 0.0f) ? 1.0f : 0.0f;

        // IoU (forward values only)
        const float c1x = px * invBlocks, c1y = py * invBlocks;
        const float c2x = tx * invBlocks, c2y = ty * invBlocks;
        const float x1a = c1x - pw * 0.5f, x2a = c1x + pw * 0.5f;
        const float y1a = c1y - ph * 0.5f, y2a = c1y + ph * 0.5f;
        const float x1b = c2x - tw * 0.5f, x2b = c2x + tw * 0.5f;
        const float y1b = c2y - th * 0.5f, y2b = c2y + th * 0.5f;
        const float dx = fminf(x2a, x2b) - fmaxf(x1a, x1b);
        const float dy = fminf(y2a, y2b) - fmaxf(y1a, y1b);
        const float inter = dx * dy;
        const float uni = pw * ph + tw * th - inter;
        const bool pos = (dx > 0.0f) && (dy > 0.0f);
        const float iou = pos ? (inter / uni) : 0.0f;

        // coord terms
        const float ex = px - tx, ey = py - ty;
        acc += COORD * m * (ex * ex + ey * ey);
        const float sw = sqrtf(pw) - sqrtf(tw);
        const float sh = sqrtf(ph) - sqrtf(th);
        acc += COORD * m * (sw * sw + sh * sh);
        // confidence terms
        const float ec = pc - iou;
        acc += m * ec * ec;
        acc += NOOBJ * (1.0f - m) * (pc * pc);
    }
}

// ---- box terms: channels 0..4, two groups per thread, deep burst ----
__global__ __launch_bounds__(256, 2) void box_kernel(
        const float4* __restrict__ in, const float4* __restrict__ tg,
        float* __restrict__ out) {
    const int tid = blockIdx.x * THREADS + threadIdx.x;  // < N4/2
    const int g0 = tid;
    const int g1 = tid + N4 / 2;
    const int b0 = (g0 >> 10) * IMG_STRIDE4 + (g0 & 1023);
    const int b1 = (g1 >> 10) * IMG_STRIDE4 + (g1 & 1023);

    // 20 loads issued before any consumption
    const float4 ap0 = in[b0 + 0 * CH_STRIDE4];
    const float4 ap1 = in[b0 + 1 * CH_STRIDE4];
    const float4 ap2 = in[b0 + 2 * CH_STRIDE4];
    const float4 ap3 = in[b0 + 3 * CH_STRIDE4];
    const float4 ap4 = in[b0 + 4 * CH_STRIDE4];
    const float4 at0 = tg[b0 + 0 * CH_STRIDE4];
    const float4 at1 = tg[b0 + 1 * CH_STRIDE4];
    const float4 at2 = tg[b0 + 2 * CH_STRIDE4];
    const float4 at3 = tg[b0 + 3 * CH_STRIDE4];
    const float4 at4 = tg[b0 + 4 * CH_STRIDE4];
    const float4 bp0 = in[b1 + 0 * CH_STRIDE4];
    const float4 bp1 = in[b1 + 1 * CH_STRIDE4];
    const float4 bp2 = in[b1 + 2 * CH_STRIDE4];
    const float4 bp3 = in[b1 + 3 * CH_STRIDE4];
    const float4 bp4 = in[b1 + 4 * CH_STRIDE4];
    const float4 bt0 = tg[b1 + 0 * CH_STRIDE4];
    const float4 bt1 = tg[b1 + 1 * CH_STRIDE4];
    const float4 bt2 = tg[b1 + 2 * CH_STRIDE4];
    const float4 bt3 = tg[b1 + 3 * CH_STRIDE4];
    const float4 bt4 = tg[b1 + 4 * CH_STRIDE4];
    __builtin_amdgcn_sched_barrier(0);   // loads may not sink below here

    float acc = 0.0f;
    boxAccum(ap0, ap1, ap2, ap3, ap4, at0, at1, at2, at3, at4, acc);
    boxAccum(bp0, bp1, bp2, bp3, bp4, bt0, bt1, bt2, bt3, bt4, acc);

    block_reduce_atomic(acc, out);
}

extern "C" void kernel_launch(void* const* d_in, const int* in_sizes, int n_in,
                              void* d_out, int out_size, void* d_ws, size_t ws_size,
                              hipStream_t stream) {
    const float4* in = (const float4*)d_in[0];
    const float4* tg = (const float4*)d_in[1];
    float* out = (float*)d_out;

    // d_out is re-poisoned to 0xAA before every timed launch -> zero it first.
    zero_out_kernel<<<1, 1, 0, stream>>>(out);

    class_kernel<<<CLASS_BLOCKS, THREADS, 0, stream>>>(in, tg, out);
    box_kernel<<<BOX_BLOCKS, THREADS, 0, stream>>>(in, tg, out);
}